// Round 2
// baseline (143.084 us; speedup 1.0000x reference)
//
#include <hip/hip_runtime.h>
#include <hip/hip_bf16.h>

// Tucker: out[a,s,t] = sum_{f,e,g} act[a,f]*state[s,e]*core[f,e,g]*state[t,g]
// A=64, S=T=1024, E=G=64, F=32.
// Stage A: Wt[a][g][e] = sum_f act[a,f]*core[f,e,g]      (bf16, 512 KB)
// Stage S: state -> bf16                                  (128 KB)
// Stage B: U[a][s][g] = sum_e state[s,e]*W_a[e,g]         (MFMA, bf16, 8 MB)
// Stage C: out[(a,s)][t] = sum_g U[(a,s)][g]*state[t,g]   (MFMA, fp32 out, 256 MiB)
//
// R1 change: swap MFMA operand roles in gemm_u/gemm_out so each lane's f32x4
// accumulator spans 4 CONSECUTIVE output columns of ONE row -> dwordx4 stores
// (was 64 scalar dword stores/wave, now 16 dwordx4). Store-granularity theory.

typedef __attribute__((ext_vector_type(8))) __bf16 bf16x8;
typedef __attribute__((ext_vector_type(4))) float f32x4;

static __device__ __forceinline__ unsigned short f2bf(float x) {
    union { float f; unsigned int u; } c; c.f = x;
    unsigned int lsb = (c.u >> 16) & 1u;
    c.u += 0x7fffu + lsb;               // round-to-nearest-even
    return (unsigned short)(c.u >> 16);
}

// ---- Stage S: convert state (1024x64 fp32) to bf16 ----
__global__ void cvt_state_bf16(const float* __restrict__ s, unsigned short* __restrict__ sb) {
    int i = blockIdx.x * blockDim.x + threadIdx.x;   // 16384 float4s
    float4 v = reinterpret_cast<const float4*>(s)[i];
    union { unsigned short u[4]; unsigned long long ull; } r;
    r.u[0] = f2bf(v.x); r.u[1] = f2bf(v.y); r.u[2] = f2bf(v.z); r.u[3] = f2bf(v.w);
    reinterpret_cast<unsigned long long*>(sb)[i] = r.ull;
}

// ---- Stage A: Wt[a][g][e] = sum_f act[a*32+f] * core[(f*64+e)*64+g] ----
__global__ void build_wt(const float* __restrict__ act, const float* __restrict__ core,
                         unsigned short* __restrict__ wt) {
    int a = blockIdx.x;           // 64 blocks
    int t = threadIdx.x;          // 256 threads
    __shared__ float af[32];
    if (t < 32) af[t] = act[a * 32 + t];
    __syncthreads();
    for (int i = 0; i < 16; ++i) {
        int idx = t + i * 256;    // 4096 (e,g) pairs
        int e = idx >> 6, g = idx & 63;
        float acc = 0.f;
#pragma unroll
        for (int f = 0; f < 32; ++f)
            acc += af[f] * core[(f * 64 + e) * 64 + g];
        wt[a * 4096 + g * 64 + e] = f2bf(acc);   // store transposed (g,e)
    }
}

// ---- Stage B: U[a][s][g] = state(s,e) . W_a(g,e)^T ----
// Swapped operands: A-frag = wt rows (g), B-frag = sb rows (s).
// D row-dim = g (4 consecutive per lane), col-dim = s  ->  8B packed-bf16 stores.
__global__ __launch_bounds__(256) void gemm_u(const unsigned short* __restrict__ sb,
                                              const unsigned short* __restrict__ wt,
                                              unsigned short* __restrict__ u) {
    int bx = blockIdx.x;                  // 256 blocks: a(64) x stile(4)
    int a = bx >> 2, st = bx & 3;
    int wid = threadIdx.x >> 6, lane = threadIdx.x & 63;
    int s0 = st * 256 + wid * 64;         // 64 s-rows per wave
    int lr = lane & 15, lk = (lane >> 4) * 8;
    int rr = (lane >> 4) * 4;
    const unsigned short* wta = wt + a * 4096;

    f32x4 acc[4][4] = {};                 // acc[mg][ns]
    bf16x8 afr[4][2], bfr[4][2];
#pragma unroll
    for (int mg = 0; mg < 4; ++mg)        // A: wt rows (g dim)
#pragma unroll
        for (int kk = 0; kk < 2; ++kk)
            afr[mg][kk] = *reinterpret_cast<const bf16x8*>(wta + (mg * 16 + lr) * 64 + kk * 32 + lk);
#pragma unroll
    for (int ns = 0; ns < 4; ++ns)        // B: state rows (s dim)
#pragma unroll
        for (int kk = 0; kk < 2; ++kk)
            bfr[ns][kk] = *reinterpret_cast<const bf16x8*>(sb + (s0 + ns * 16 + lr) * 64 + kk * 32 + lk);
#pragma unroll
    for (int kk = 0; kk < 2; ++kk)
#pragma unroll
        for (int mg = 0; mg < 4; ++mg)
#pragma unroll
            for (int ns = 0; ns < 4; ++ns)
                acc[mg][ns] = __builtin_amdgcn_mfma_f32_16x16x32_bf16(afr[mg][kk], bfr[ns][kk], acc[mg][ns], 0, 0, 0);

    // lane holds U[s = s0+ns*16+lr][g = mg*16+rr+q], q=0..3 -> pack 4 bf16 = 8B store
#pragma unroll
    for (int ns = 0; ns < 4; ++ns) {
        int srow = s0 + ns * 16 + lr;
        unsigned short* urow = u + (size_t)a * 65536 + (size_t)srow * 64;
#pragma unroll
        for (int mg = 0; mg < 4; ++mg) {
            union { unsigned short h[4]; unsigned long long ull; } pk;
#pragma unroll
            for (int q = 0; q < 4; ++q) pk.h[q] = f2bf(acc[mg][ns][q]);
            *reinterpret_cast<unsigned long long*>(urow + mg * 16 + rr) = pk.ull;
        }
    }
}

// ---- Stage C: out[(a,s)][t] = U((a,s),g) . state(t,g)^T ----
// Swapped operands: A-frag = sb rows (t), B-frag = u rows (out rows).
// D row-dim = t (4 consecutive per lane), col-dim = out row -> dwordx4 stores.
__global__ __launch_bounds__(256) void gemm_out(const unsigned short* __restrict__ u,
                                                const unsigned short* __restrict__ sb,
                                                float* __restrict__ out) {
    int bx = blockIdx.x;                  // 4096 blocks: 512 mb x 8 nb
    int mb = bx >> 3, nb = bx & 7;        // consecutive blocks share the U tile (L2 reuse)
    int wid = threadIdx.x >> 6, lane = threadIdx.x & 63;
    int wr = wid >> 1, wc = wid & 1;      // 2x2 waves of 64x64
    int R0 = mb * 128 + wr * 64;          // out-row base ((a,s) flat)
    int C0 = nb * 128 + wc * 64;          // t base
    int lr = lane & 15, lk = (lane >> 4) * 8;
    int rr = (lane >> 4) * 4;

    f32x4 acc[4][4] = {};                 // acc[m][n]: m = t-frag, n = row-frag
    bf16x8 afr[4][2], bfr[4][2];
#pragma unroll
    for (int m = 0; m < 4; ++m)           // A: state rows (t dim)
#pragma unroll
        for (int kk = 0; kk < 2; ++kk)
            afr[m][kk] = *reinterpret_cast<const bf16x8*>(sb + (C0 + m * 16 + lr) * 64 + kk * 32 + lk);
#pragma unroll
    for (int n = 0; n < 4; ++n)           // B: U rows (out-row dim)
#pragma unroll
        for (int kk = 0; kk < 2; ++kk)
            bfr[n][kk] = *reinterpret_cast<const bf16x8*>(u + (size_t)(R0 + n * 16 + lr) * 64 + kk * 32 + lk);
#pragma unroll
    for (int kk = 0; kk < 2; ++kk)
#pragma unroll
        for (int m = 0; m < 4; ++m)
#pragma unroll
            for (int n = 0; n < 4; ++n)
                acc[m][n] = __builtin_amdgcn_mfma_f32_16x16x32_bf16(afr[m][kk], bfr[n][kk], acc[m][n], 0, 0, 0);

    // lane holds out[R0+n*16+lr][C0+m*16+rr+q], q=0..3 -> one dwordx4 store
#pragma unroll
    for (int n = 0; n < 4; ++n) {
        float* orow = out + (size_t)(R0 + n * 16 + lr) * 1024 + C0;
#pragma unroll
        for (int m = 0; m < 4; ++m) {
            float4 v; v.x = acc[m][n][0]; v.y = acc[m][n][1]; v.z = acc[m][n][2]; v.w = acc[m][n][3];
            *reinterpret_cast<float4*>(orow + m * 16 + rr) = v;
        }
    }
}

extern "C" void kernel_launch(void* const* d_in, const int* in_sizes, int n_in,
                              void* d_out, int out_size, void* d_ws, size_t ws_size,
                              hipStream_t stream) {
    const float* state = (const float*)d_in[0];   // 1024 x 64
    const float* act   = (const float*)d_in[1];   // 64 x 32
    const float* core  = (const float*)d_in[2];   // 32 x 64 x 64
    float* out = (float*)d_out;                   // 64 x 1024 x 1024

    unsigned short* sb = (unsigned short*)d_ws;   // state bf16: 65536 (128 KB)
    unsigned short* wt = sb + 65536;              // Wt bf16:   262144 (512 KB)
    unsigned short* u  = wt + 262144;             // U bf16:    4194304 (8 MB)

    cvt_state_bf16<<<64, 256, 0, stream>>>(state, sb);
    build_wt<<<64, 256, 0, stream>>>(act, core, wt);
    gemm_u<<<256, 256, 0, stream>>>(sb, wt, u);
    gemm_out<<<4096, 256, 0, stream>>>(u, sb, out);
}

// Round 3
// 127.244 us; speedup vs baseline: 1.1245x; 1.1245x over previous
//
#include <hip/hip_runtime.h>
#include <hip/hip_bf16.h>

// Tucker: out[a,s,t] = sum_{f,e,g} act[a,f]*state[s,e]*core[f,e,g]*state[t,g]
// A=64, S=T=1024, E=G=64, F=32.
// prep:   state->bf16 (sb) and Wt[a][g][e]=sum_f act*core (bf16)
// gemm_u: U[a][s][g] = state(s,e) . W_a(g,e)^T          (MFMA, bf16, 8 MB)
// gemm_out: out[(a,s)][t] = U . state(t,g)^T            (MFMA, fp32, 256 MiB)
//
// R2 changes (duty-cycle theory): gemm_out restructured as streaming m-loop
// (low VGPR, stores interleaved), nontemporal out stores (no L2 churn),
// XCD-chunked block mapping (per-XCD u slice = 1 MB -> L2 resident).

typedef __attribute__((ext_vector_type(8))) __bf16 bf16x8;
typedef __attribute__((ext_vector_type(4))) float f32x4;

static __device__ __forceinline__ unsigned short f2bf(float x) {
    union { float f; unsigned int u; } c; c.f = x;
    unsigned int lsb = (c.u >> 16) & 1u;
    c.u += 0x7fffu + lsb;               // round-to-nearest-even
    return (unsigned short)(c.u >> 16);
}

// ---- prep: fused state->bf16 conversion + Wt build ----
__global__ void prep(const float* __restrict__ state, const float* __restrict__ act,
                     const float* __restrict__ core,
                     unsigned short* __restrict__ sb, unsigned short* __restrict__ wt) {
    int a = blockIdx.x;           // 64 blocks
    int t = threadIdx.x;          // 256 threads
    {   // state cvt: 16384 float4s, 256 per block
        int i = a * 256 + t;
        float4 v = reinterpret_cast<const float4*>(state)[i];
        union { unsigned short u[4]; unsigned long long ull; } r;
        r.u[0] = f2bf(v.x); r.u[1] = f2bf(v.y); r.u[2] = f2bf(v.z); r.u[3] = f2bf(v.w);
        reinterpret_cast<unsigned long long*>(sb)[i] = r.ull;
    }
    __shared__ float af[32];
    if (t < 32) af[t] = act[a * 32 + t];
    __syncthreads();
    for (int i = 0; i < 16; ++i) {
        int idx = t + i * 256;    // 4096 (e,g) pairs
        int e = idx >> 6, g = idx & 63;
        float acc = 0.f;
#pragma unroll
        for (int f = 0; f < 32; ++f)
            acc += af[f] * core[(f * 64 + e) * 64 + g];
        wt[a * 4096 + g * 64 + e] = f2bf(acc);   // store transposed (g,e)
    }
}

// ---- gemm_u: U[a][s][g] = state(s,e) . W_a(g,e)^T ----
// A-frag = wt rows (g), B-frag = sb rows (s) -> lane holds 4 consecutive g.
__global__ __launch_bounds__(256) void gemm_u(const unsigned short* __restrict__ sb,
                                              const unsigned short* __restrict__ wt,
                                              unsigned short* __restrict__ u) {
    int bx = blockIdx.x;                  // 256 blocks: a(64) x stile(4)
    int a = bx >> 2, st = bx & 3;
    int wid = threadIdx.x >> 6, lane = threadIdx.x & 63;
    int s0 = st * 256 + wid * 64;
    int lr = lane & 15, lk = (lane >> 4) * 8;
    int rr = (lane >> 4) * 4;
    const unsigned short* wta = wt + a * 4096;

    f32x4 acc[4][4] = {};                 // acc[mg][ns]
    bf16x8 afr[4][2], bfr[4][2];
#pragma unroll
    for (int mg = 0; mg < 4; ++mg)
#pragma unroll
        for (int kk = 0; kk < 2; ++kk)
            afr[mg][kk] = *reinterpret_cast<const bf16x8*>(wta + (mg * 16 + lr) * 64 + kk * 32 + lk);
#pragma unroll
    for (int ns = 0; ns < 4; ++ns)
#pragma unroll
        for (int kk = 0; kk < 2; ++kk)
            bfr[ns][kk] = *reinterpret_cast<const bf16x8*>(sb + (s0 + ns * 16 + lr) * 64 + kk * 32 + lk);
#pragma unroll
    for (int kk = 0; kk < 2; ++kk)
#pragma unroll
        for (int mg = 0; mg < 4; ++mg)
#pragma unroll
            for (int ns = 0; ns < 4; ++ns)
                acc[mg][ns] = __builtin_amdgcn_mfma_f32_16x16x32_bf16(afr[mg][kk], bfr[ns][kk], acc[mg][ns], 0, 0, 0);

#pragma unroll
    for (int ns = 0; ns < 4; ++ns) {
        int srow = s0 + ns * 16 + lr;
        unsigned short* urow = u + (size_t)a * 65536 + (size_t)srow * 64;
#pragma unroll
        for (int mg = 0; mg < 4; ++mg) {
            union { unsigned short h[4]; unsigned long long ull; } pk;
#pragma unroll
            for (int q = 0; q < 4; ++q) pk.h[q] = f2bf(acc[mg][ns][q]);
            *reinterpret_cast<unsigned long long*>(urow + mg * 16 + rr) = pk.ull;
        }
    }
}

// ---- gemm_out: out[(a,s)][t] = U((a,s),g) . state(t,g)^T ----
// Streaming form: u-rows (bfr) loaded once, then per t-fragment
// {prefetch next sb frag -> 8 MFMA -> 4 nontemporal dwordx4 stores}.
__global__ __launch_bounds__(256) void gemm_out(const unsigned short* __restrict__ u,
                                                const unsigned short* __restrict__ sb,
                                                float* __restrict__ out) {
    int bx = blockIdx.x;                  // 4096 blocks
    // XCD-chunked mapping: xcd = bx&7 (dispatch round-robin); each XCD owns a
    // contiguous mb range (64 mb -> 1 MB of u, L2-resident) x all 8 nb.
    int xcd = bx & 7;
    int idx = bx >> 3;                    // 0..511
    int mb = xcd * 64 + (idx >> 3);       // 0..511
    int nb = idx & 7;                     // 0..7
    int wid = threadIdx.x >> 6, lane = threadIdx.x & 63;
    int wr = wid >> 1, wc = wid & 1;      // 2x2 waves of 64x64
    int R0 = mb * 128 + wr * 64;          // out-row base ((a,s) flat)
    int C0 = nb * 128 + wc * 64;          // t base
    int lr = lane & 15, lk = (lane >> 4) * 8;
    int rr = (lane >> 4) * 4;

    bf16x8 bfr[4][2];                     // u rows, reused across all m
#pragma unroll
    for (int n = 0; n < 4; ++n)
#pragma unroll
        for (int kk = 0; kk < 2; ++kk)
            bfr[n][kk] = *reinterpret_cast<const bf16x8*>(u + (size_t)(R0 + n * 16 + lr) * 64 + kk * 32 + lk);

    bf16x8 a0 = *reinterpret_cast<const bf16x8*>(sb + (C0 + lr) * 64 + lk);
    bf16x8 a1 = *reinterpret_cast<const bf16x8*>(sb + (C0 + lr) * 64 + 32 + lk);

#pragma unroll
    for (int m = 0; m < 4; ++m) {
        bf16x8 p0 = a0, p1 = a1;
        if (m < 3) {                      // prefetch next t-fragment (folds at compile time)
            a0 = *reinterpret_cast<const bf16x8*>(sb + (C0 + (m + 1) * 16 + lr) * 64 + lk);
            a1 = *reinterpret_cast<const bf16x8*>(sb + (C0 + (m + 1) * 16 + lr) * 64 + 32 + lk);
        }
        f32x4 acc[4] = {};
#pragma unroll
        for (int n = 0; n < 4; ++n) {
            acc[n] = __builtin_amdgcn_mfma_f32_16x16x32_bf16(p0, bfr[n][0], acc[n], 0, 0, 0);
            acc[n] = __builtin_amdgcn_mfma_f32_16x16x32_bf16(p1, bfr[n][1], acc[n], 0, 0, 0);
        }
#pragma unroll
        for (int n = 0; n < 4; ++n) {
            f32x4* dst = reinterpret_cast<f32x4*>(out + (size_t)(R0 + n * 16 + lr) * 1024 + C0 + m * 16 + rr);
            __builtin_nontemporal_store(acc[n], dst);
        }
    }
}

extern "C" void kernel_launch(void* const* d_in, const int* in_sizes, int n_in,
                              void* d_out, int out_size, void* d_ws, size_t ws_size,
                              hipStream_t stream) {
    const float* state = (const float*)d_in[0];   // 1024 x 64
    const float* act   = (const float*)d_in[1];   // 64 x 32
    const float* core  = (const float*)d_in[2];   // 32 x 64 x 64
    float* out = (float*)d_out;                   // 64 x 1024 x 1024

    unsigned short* sb = (unsigned short*)d_ws;   // state bf16: 65536 (128 KB)
    unsigned short* wt = sb + 65536;              // Wt bf16:   262144 (512 KB)
    unsigned short* u  = wt + 262144;             // U bf16:    4194304 (8 MB)

    prep<<<64, 256, 0, stream>>>(state, act, core, sb, wt);
    gemm_u<<<256, 256, 0, stream>>>(sb, wt, u);
    gemm_out<<<4096, 256, 0, stream>>>(u, sb, out);
}